// Round 9
// baseline (148.016 us; speedup 1.0000x reference)
//
#include <hip/hip_runtime.h>
#include <hip/hip_fp16.h>

#define NB 4
#define NT 16
#define NN 2048
#define NM 64
#define NK 32
#define NC 1024

// ROCm 7.2 hip_fp16.h has no __hmax2 — emit v_pk_max_f16 directly.
static __device__ inline __half2 h2max(__half2 a, __half2 b) {
    unsigned int ai = *(unsigned int*)&a, bi = *(unsigned int*)&b, di;
    asm("v_pk_max_f16 %0, %1, %2" : "=v"(di) : "v"(ai), "v"(bi));
    return *(__half2*)&di;
}

// DPP-based wave64 max reduce step (verified R5-R8): after the chain,
// lane 63 holds the wave max.
#define DPP_MAX_STEP(v, ctrl)                                                   \
    do {                                                                        \
        const int _mv = __builtin_amdgcn_update_dpp(                            \
            __float_as_int(v), __float_as_int(v), (ctrl), 0xf, 0xf, false);     \
        (v) = fmaxf((v), __int_as_float(_mv));                                  \
    } while (0)

static __device__ inline float readlane_f(float x, int l) {
    return __int_as_float(__builtin_amdgcn_readlane(__float_as_int(x), l));
}

// ---------------------------------------------------------------------------
// Kernel A: FPS — ONE WAVE per frame (64 blocks x 64 thr), 32 contiguous
// points per lane in registers. No barriers, no cross-wave exchange: the
// entire round is in-wave (d2 update -> max tree -> 4 independent
// first-match scans -> DPP value max -> ballot lowest-lane tie-break ->
// uniform ds_read of winner coords). Same-wave LDS ordering needs no
// __syncthreads; anchor stores are fire-and-forget (no drain). Tie-break
// semantics and _rn arithmetic identical to the verified R2-R8 versions:
// in-lane first-index wins (ascending strict >, scans pick smallest j),
// cross-lane lowest lane wins = globally smallest index.
// ---------------------------------------------------------------------------
__global__ __launch_bounds__(64, 1) void fps_kernel(const float* __restrict__ xyzs,
                                                    float* __restrict__ out_xyz) {
    const int bt = blockIdx.x;
    const float* pts = xyzs + (size_t)bt * NN * 3;
    __shared__ __align__(16) float sP[NN * 3];
    const int lane = threadIdx.x;
    // load 32 points (96 floats) per lane; stage to LDS as 24 b128 writes
    float arr[96];
    {
        const float4* pv = (const float4*)pts + (size_t)lane * 24;
        #pragma unroll
        for (int i = 0; i < 24; ++i) {
            const float4 f = pv[i];
            ((float4*)sP)[lane * 24 + i] = f;
            arr[4 * i + 0] = f.x; arr[4 * i + 1] = f.y; arr[4 * i + 2] = f.z; arr[4 * i + 3] = f.w;
        }
    }
    float px[32], py[32], pz[32], d2[32];
    #pragma unroll
    for (int p = 0; p < 32; ++p) {
        px[p] = arr[3 * p + 0]; py[p] = arr[3 * p + 1]; pz[p] = arr[3 * p + 2];
        d2[p] = 1e10f;
    }
    // initial anchor = point 0 (reference: last = 0)
    float ax = readlane_f(px[0], 0), ay = readlane_f(py[0], 0), az = readlane_f(pz[0], 0);
    for (int it = 0; it < NM; ++it) {
        // emit current anchor (pre-update last, matching the reference scan)
        if (lane < 3) {
            const float val = lane == 0 ? ax : (lane == 1 ? ay : az);
            out_xyz[(bt * NM + it) * 3 + lane] = val;
        }
        // d2 update: 32 independent chains, issue-pipelined
        #pragma unroll
        for (int p = 0; p < 32; ++p) {
            const float dx = __fsub_rn(px[p], ax), dy = __fsub_rn(py[p], ay), dz = __fsub_rn(pz[p], az);
            const float d = __fadd_rn(__fadd_rn(__fmul_rn(dx, dx), __fmul_rn(dy, dy)), __fmul_rn(dz, dz));
            d2[p] = fminf(d2[p], d);
        }
        // lane-local max value via 31-op tree (log depth)
        float t16[16], t8[8], t4[4], t2[2];
        #pragma unroll
        for (int i = 0; i < 16; ++i) t16[i] = fmaxf(d2[i], d2[i + 16]);
        #pragma unroll
        for (int i = 0; i < 8; ++i) t8[i] = fmaxf(t16[i], t16[i + 8]);
        #pragma unroll
        for (int i = 0; i < 4; ++i) t4[i] = fmaxf(t8[i], t8[i + 4]);
        t2[0] = fmaxf(t4[0], t4[2]); t2[1] = fmaxf(t4[1], t4[3]);
        const float bv = fmaxf(t2[0], t2[1]);
        // first j with d2[j]==bv: 4 independent descending scans, then min
        int bq0 = 64, bq1 = 64, bq2 = 64, bq3 = 64;
        #pragma unroll
        for (int jj = 7; jj >= 0; --jj) {
            bq0 = (d2[jj] == bv) ? jj : bq0;
            bq1 = (d2[8 + jj] == bv) ? (8 + jj) : bq1;
            bq2 = (d2[16 + jj] == bv) ? (16 + jj) : bq2;
            bq3 = (d2[24 + jj] == bv) ? (24 + jj) : bq3;
        }
        const int bj = min(min(bq0, bq1), min(bq2, bq3));
        // wave value-max via DPP, lowest-lane tie-break via ballot
        float v = bv;
        DPP_MAX_STEP(v, 0x111);   // row_shr:1
        DPP_MAX_STEP(v, 0x112);   // row_shr:2
        DPP_MAX_STEP(v, 0x114);   // row_shr:4
        DPP_MAX_STEP(v, 0x118);   // row_shr:8
        DPP_MAX_STEP(v, 0x142);   // row_bcast:15
        DPP_MAX_STEP(v, 0x143);   // row_bcast:31
        const float vmax = readlane_f(v, 63);
        const unsigned long long tied = __ballot(bv == vmax);
        const int src = (int)(__ffsll((long long)tied) - 1);   // lowest lane = lowest idx
        const int last = __builtin_amdgcn_readlane(lane * 32 + bj, src);
        // next anchor coords: uniform LDS read, same-wave ordering (no barrier)
        ax = sP[3 * last + 0]; ay = sP[3 * last + 1]; az = sP[3 * last + 2];
    }
}

// ---------------------------------------------------------------------------
// Kernel B: ball query only (unchanged, verified R4-R8). One wave per
// (bt,m,tap) query -> 48 packed half2 displacement words into d_ws.
// ---------------------------------------------------------------------------
__global__ __launch_bounds__(256) void bq_kernel(const float* __restrict__ xyzs,
                                                 const float* __restrict__ anchors,
                                                 unsigned int* __restrict__ disp) {
    const int tid = threadIdx.x;
    const int lane = tid & 63, w = tid >> 6;
    const int q = blockIdx.x * 4 + w;      // (bt*NM + m)*3 + tap
    const int bt = q / (NM * 3);
    const int r = q - bt * (NM * 3);
    const int m = r / 3, tap = r - m * 3;
    const int b = bt >> 4, t = bt & 15;
    __shared__ float sD[4][3][NK];
    const float ax = anchors[(bt * NM + m) * 3 + 0];
    const float ay = anchors[(bt * NM + m) * 3 + 1];
    const float az = anchors[(bt * NM + m) * 3 + 2];
    int tsrc = t + tap - 1;
    tsrc = tsrc < 0 ? 0 : (tsrc > NT - 1 ? NT - 1 : tsrc);
    const float* npts = xyzs + ((size_t)(b * NT + tsrc)) * NN * 3;
    int cnt = 0;
    for (int rr = 0; rr < NN / 64 && cnt < NK; ++rr) {
        const int n = rr * 64 + lane;
        const float dx = __fsub_rn(npts[n * 3 + 0], ax);
        const float dy = __fsub_rn(npts[n * 3 + 1], ay);
        const float dz = __fsub_rn(npts[n * 3 + 2], az);
        const float d2v = __fadd_rn(__fadd_rn(__fmul_rn(dx, dx), __fmul_rn(dy, dy)), __fmul_rn(dz, dz));
        const bool valid = d2v < 0.49f;    // f32(0.7*0.7)
        const unsigned long long mask = __ballot(valid);
        const int pos = cnt + (int)__popcll(mask & ((1ull << lane) - 1ull));
        if (valid && pos < NK) {
            sD[w][0][pos] = dx; sD[w][1][pos] = dy; sD[w][2][pos] = dz;
        }
        cnt += (int)__popcll(mask);
    }
    if (cnt < NK) {   // pad with first valid disp (or neigh[0]-anchor if none)
        float fx, fy, fz;
        if (cnt > 0) {
            fx = sD[w][0][0]; fy = sD[w][1][0]; fz = sD[w][2][0];
        } else {
            fx = __fsub_rn(npts[0], ax); fy = __fsub_rn(npts[1], ay); fz = __fsub_rn(npts[2], az);
        }
        if (lane >= cnt && lane < NK) {
            sD[w][0][lane] = fx; sD[w][1][lane] = fy; sD[w][2][lane] = fz;
        }
    }
    // repack f32 -> half2 pairs along k; layout [x:16][y:16][z:16] u32 words
    if (lane < 48) {
        const int c = lane >> 4, j = lane & 15;
        const __half2 hv = __float22half2_rn(make_float2(sD[w][c][2 * j], sD[w][c][2 * j + 1]));
        disp[(size_t)q * 48 + lane] = *(const unsigned int*)&hv;
    }
}

// ---------------------------------------------------------------------------
// Kernel C: conv + k-maxpool + tap-sum — EXACT R5 version (best measured).
// 1024 blocks x 256 thr. Block = (bt, 16-m range, 256-channel slice);
// wave = 4 m; lane = 4 channels. No LDS, no barriers.
// ---------------------------------------------------------------------------
__global__ __launch_bounds__(256) void conv_kernel(const unsigned int* __restrict__ disp,
                                                   const float* __restrict__ wd,
                                                   float* __restrict__ feat) {
    const int blk = blockIdx.x;            // 1024 = 64bt * 4mh * 4cq
    const int bt = blk >> 4;
    const int inner = blk & 15;
    const int mh = inner >> 2, cq = inner & 3;
    const int tid = threadIdx.x;
    const int lane = tid & 63, w = tid >> 6;
    const int m0 = mh * 16 + w * 4;
    const int c0 = cq * 256 + lane;        // channels c0 + {0,64,128,192}
    float4 wv[4]; __half2 wx[4], wy[4], wz[4];
    #pragma unroll
    for (int r = 0; r < 4; ++r) {
        wv[r] = ((const float4*)wd)[c0 + 64 * r];
        wx[r] = __float2half2_rn(wv[r].x);
        wy[r] = __float2half2_rn(wv[r].y);
        wz[r] = __float2half2_rn(wv[r].z);
    }
    float acc[4][4];
    #pragma unroll
    for (int r = 0; r < 4; ++r)
        #pragma unroll
        for (int mi = 0; mi < 4; ++mi) acc[r][mi] = 0.0f;

    #pragma unroll
    for (int mi = 0; mi < 4; ++mi) {
        #pragma unroll
        for (int tap = 0; tap < 3; ++tap) {
            const uint4* dp = (const uint4*)(disp + ((size_t)((bt * NM + m0 + mi) * 3 + tap)) * 48);
            uint4 u[12];
            #pragma unroll
            for (int i = 0; i < 12; ++i) u[i] = dp[i];
            const unsigned int* uw = (const unsigned int*)u;   // X[0..15] Y[16..31] Z[32..47]
            __half2 a[4];
            #pragma unroll
            for (int j = 0; j < 16; ++j) {
                const __half2 hx = *(const __half2*)&uw[j];
                const __half2 hy = *(const __half2*)&uw[16 + j];
                const __half2 hz = *(const __half2*)&uw[32 + j];
                #pragma unroll
                for (int r = 0; r < 4; ++r) {
                    const __half2 s = __hfma2(wx[r], hx, __hfma2(wy[r], hy, __hmul2(wz[r], hz)));
                    a[r] = (j == 0) ? s : h2max(a[r], s);
                }
            }
            const float dtf = (float)(tap - 1);
            #pragma unroll
            for (int r = 0; r < 4; ++r) {
                const float mx = fmaxf(__low2float(a[r]), __high2float(a[r]));
                acc[r][mi] += fmaxf(0.0f, mx + wv[r].w * dtf);   // relu/max/+const commute
            }
        }
    }
    #pragma unroll
    for (int r = 0; r < 4; ++r) {
        float* dst = feat + ((size_t)bt * NC + c0 + 64 * r) * NM + m0;
        *(float4*)dst = make_float4(acc[r][0], acc[r][1], acc[r][2], acc[r][3]);
    }
}

extern "C" void kernel_launch(void* const* d_in, const int* in_sizes, int n_in,
                              void* d_out, int out_size, void* d_ws, size_t ws_size,
                              hipStream_t stream) {
    const float* xyzs = (const float*)d_in[0];
    const float* wd   = (const float*)d_in[1];
    float* out_xyz = (float*)d_out;
    float* featp   = out_xyz + NB * NT * NM * 3;         // new_features region
    unsigned int* dispw = (unsigned int*)d_ws;           // 12288*48*4 B = 2.36 MB
    hipLaunchKernelGGL(fps_kernel, dim3(NB * NT), dim3(64), 0, stream, xyzs, out_xyz);
    hipLaunchKernelGGL(bq_kernel, dim3(NB * NT * NM * 3 / 4), dim3(256), 0, stream,
                       xyzs, out_xyz, dispw);
    hipLaunchKernelGGL(conv_kernel, dim3(1024), dim3(256), 0, stream,
                       dispw, wd, featp);
}

// Round 10
// 133.203 us; speedup vs baseline: 1.1112x; 1.1112x over previous
//
#include <hip/hip_runtime.h>
#include <hip/hip_fp16.h>

#define NB 4
#define NT 16
#define NN 2048
#define NM 64
#define NK 32
#define NC 1024

// ROCm 7.2 hip_fp16.h has no __hmax2 — emit v_pk_max_f16 directly.
static __device__ inline __half2 h2max(__half2 a, __half2 b) {
    unsigned int ai = *(unsigned int*)&a, bi = *(unsigned int*)&b, di;
    asm("v_pk_max_f16 %0, %1, %2" : "=v"(di) : "v"(ai), "v"(bi));
    return *(__half2*)&di;
}
static __device__ inline unsigned long long u64max(unsigned long long a, unsigned long long b) {
    return a > b ? a : b;
}

// ---------------------------------------------------------------------------
// Kernel A: FPS — exact R5 version (best measured: ~30 us). One 256-thr
// block (4 waves) per frame; thread tid owns contiguous [tid*8, tid*8+8);
// wave argmax = 6-step shfl_xor value butterfly + ballot first-index
// tie-break; cross-wave combine via u64 (d2bits<<32 | 2047-idx) in parity
// LDS, one barrier per round. _rn arithmetic, bit-exact vs reference.
// ---------------------------------------------------------------------------
__global__ __launch_bounds__(256) void fps_kernel(const float* __restrict__ xyzs,
                                                  float* __restrict__ out_xyz) {
    const int bt = blockIdx.x;
    const float* pts = xyzs + (size_t)bt * NN * 3;
    __shared__ __align__(16) float sP[NN * 3];
    __shared__ unsigned long long sPart[2][4];
    __shared__ float sAnchor[NM * 3];
    const int tid = threadIdx.x;
    const int lane = tid & 63, wave = tid >> 6;
    float wpt[24];
    {
        const float4* pv = (const float4*)pts + (size_t)tid * 6;
        #pragma unroll
        for (int i = 0; i < 6; ++i) {
            const float4 f = pv[i];
            ((float4*)sP)[tid * 6 + i] = f;
            wpt[4 * i + 0] = f.x; wpt[4 * i + 1] = f.y; wpt[4 * i + 2] = f.z; wpt[4 * i + 3] = f.w;
        }
    }
    float px[8], py[8], pz[8], d2[8];
    #pragma unroll
    for (int j = 0; j < 8; ++j) {
        px[j] = wpt[3 * j + 0]; py[j] = wpt[3 * j + 1]; pz[j] = wpt[3 * j + 2];
        d2[j] = 1e10f;
    }
    __syncthreads();
    int last = 0;
    for (int it = 0; it < NM; ++it) {
        const float lx = sP[last * 3 + 0], ly = sP[last * 3 + 1], lz = sP[last * 3 + 2];
        if (tid == 0) {
            sAnchor[it * 3 + 0] = lx; sAnchor[it * 3 + 1] = ly; sAnchor[it * 3 + 2] = lz;
        }
        float bv = -1.0f; int bp = 0;
        #pragma unroll
        for (int j = 0; j < 8; ++j) {
            const float dx = __fsub_rn(px[j], lx), dy = __fsub_rn(py[j], ly), dz = __fsub_rn(pz[j], lz);
            const float d = __fadd_rn(__fadd_rn(__fmul_rn(dx, dx), __fmul_rn(dy, dy)), __fmul_rn(dz, dz));
            d2[j] = fminf(d2[j], d);
            if (d2[j] > bv) { bv = d2[j]; bp = tid * 8 + j; }  // strict > -> first j wins
        }
        float v = bv;
        #pragma unroll
        for (int off = 32; off > 0; off >>= 1)
            v = fmaxf(v, __shfl_xor(v, off, 64));
        const unsigned long long tied = __ballot(bv == v);
        const int srcLane = (int)(__ffsll((long long)tied) - 1);   // lowest lane = lowest idx
        const int idxw = __shfl(bp, srcLane, 64);
        if (lane == 0)
            sPart[it & 1][wave] = ((unsigned long long)__float_as_uint(v) << 32)
                                | (unsigned)(NN - 1 - idxw);
        __syncthreads();
        const unsigned long long key =
            u64max(u64max(sPart[it & 1][0], sPart[it & 1][1]),
                   u64max(sPart[it & 1][2], sPart[it & 1][3]));
        last = NN - 1 - (int)(key & 0xffffffffull);
    }
    __syncthreads();
    for (int i = tid; i < NM * 3; i += 256)
        out_xyz[bt * NM * 3 + i] = sAnchor[i];
}

// ---------------------------------------------------------------------------
// Kernel B: ball query only (unchanged, verified R4-R9). One wave per
// (bt,m,tap) query -> 48 packed half2 displacement words into d_ws.
// ---------------------------------------------------------------------------
__global__ __launch_bounds__(256) void bq_kernel(const float* __restrict__ xyzs,
                                                 const float* __restrict__ anchors,
                                                 unsigned int* __restrict__ disp) {
    const int tid = threadIdx.x;
    const int lane = tid & 63, w = tid >> 6;
    const int q = blockIdx.x * 4 + w;      // (bt*NM + m)*3 + tap
    const int bt = q / (NM * 3);
    const int r = q - bt * (NM * 3);
    const int m = r / 3, tap = r - m * 3;
    const int b = bt >> 4, t = bt & 15;
    __shared__ float sD[4][3][NK];
    const float ax = anchors[(bt * NM + m) * 3 + 0];
    const float ay = anchors[(bt * NM + m) * 3 + 1];
    const float az = anchors[(bt * NM + m) * 3 + 2];
    int tsrc = t + tap - 1;
    tsrc = tsrc < 0 ? 0 : (tsrc > NT - 1 ? NT - 1 : tsrc);
    const float* npts = xyzs + ((size_t)(b * NT + tsrc)) * NN * 3;
    int cnt = 0;
    for (int rr = 0; rr < NN / 64 && cnt < NK; ++rr) {
        const int n = rr * 64 + lane;
        const float dx = __fsub_rn(npts[n * 3 + 0], ax);
        const float dy = __fsub_rn(npts[n * 3 + 1], ay);
        const float dz = __fsub_rn(npts[n * 3 + 2], az);
        const float d2v = __fadd_rn(__fadd_rn(__fmul_rn(dx, dx), __fmul_rn(dy, dy)), __fmul_rn(dz, dz));
        const bool valid = d2v < 0.49f;    // f32(0.7*0.7)
        const unsigned long long mask = __ballot(valid);
        const int pos = cnt + (int)__popcll(mask & ((1ull << lane) - 1ull));
        if (valid && pos < NK) {
            sD[w][0][pos] = dx; sD[w][1][pos] = dy; sD[w][2][pos] = dz;
        }
        cnt += (int)__popcll(mask);
    }
    if (cnt < NK) {   // pad with first valid disp (or neigh[0]-anchor if none)
        float fx, fy, fz;
        if (cnt > 0) {
            fx = sD[w][0][0]; fy = sD[w][1][0]; fz = sD[w][2][0];
        } else {
            fx = __fsub_rn(npts[0], ax); fy = __fsub_rn(npts[1], ay); fz = __fsub_rn(npts[2], az);
        }
        if (lane >= cnt && lane < NK) {
            sD[w][0][lane] = fx; sD[w][1][lane] = fy; sD[w][2][lane] = fz;
        }
    }
    // repack f32 -> half2 pairs along k; layout [x:16][y:16][z:16] u32 words
    if (lane < 48) {
        const int c = lane >> 4, j = lane & 15;
        const __half2 hv = __float22half2_rn(make_float2(sD[w][c][2 * j], sD[w][c][2 * j + 1]));
        disp[(size_t)q * 48 + lane] = *(const unsigned int*)&hv;
    }
}

// ---------------------------------------------------------------------------
// Kernel C: conv + k-maxpool + tap-sum — R5 version with ONE change: the
// block-index decode is swizzled so the 4 blocks sharing the same disp
// tiles (same bt,mh; cq=0..3) are 256 apart in dispatch index (== same
// mod 8 -> same XCD L2) instead of adjacent (4 XCDs -> 4x tile refetch,
// the R4 FETCH=9.3MB signature). Pure index remap, no other change.
// ---------------------------------------------------------------------------
__global__ __launch_bounds__(256) void conv_kernel(const unsigned int* __restrict__ disp,
                                                   const float* __restrict__ wd,
                                                   float* __restrict__ feat) {
    const int blk = blockIdx.x;            // 1024 = 4cq(outer) * 64bt * 4mh
    const int cq = blk >> 8;               // swizzle: cq outermost
    const int rdec = blk & 255;
    const int bt = rdec >> 2, mh = rdec & 3;
    const int tid = threadIdx.x;
    const int lane = tid & 63, w = tid >> 6;
    const int m0 = mh * 16 + w * 4;
    const int c0 = cq * 256 + lane;        // channels c0 + {0,64,128,192}
    float4 wv[4]; __half2 wx[4], wy[4], wz[4];
    #pragma unroll
    for (int r = 0; r < 4; ++r) {
        wv[r] = ((const float4*)wd)[c0 + 64 * r];
        wx[r] = __float2half2_rn(wv[r].x);
        wy[r] = __float2half2_rn(wv[r].y);
        wz[r] = __float2half2_rn(wv[r].z);
    }
    float acc[4][4];
    #pragma unroll
    for (int r = 0; r < 4; ++r)
        #pragma unroll
        for (int mi = 0; mi < 4; ++mi) acc[r][mi] = 0.0f;

    #pragma unroll
    for (int mi = 0; mi < 4; ++mi) {
        #pragma unroll
        for (int tap = 0; tap < 3; ++tap) {
            const uint4* dp = (const uint4*)(disp + ((size_t)((bt * NM + m0 + mi) * 3 + tap)) * 48);
            uint4 u[12];
            #pragma unroll
            for (int i = 0; i < 12; ++i) u[i] = dp[i];
            const unsigned int* uw = (const unsigned int*)u;   // X[0..15] Y[16..31] Z[32..47]
            __half2 a[4];
            #pragma unroll
            for (int j = 0; j < 16; ++j) {
                const __half2 hx = *(const __half2*)&uw[j];
                const __half2 hy = *(const __half2*)&uw[16 + j];
                const __half2 hz = *(const __half2*)&uw[32 + j];
                #pragma unroll
                for (int r = 0; r < 4; ++r) {
                    const __half2 s = __hfma2(wx[r], hx, __hfma2(wy[r], hy, __hmul2(wz[r], hz)));
                    a[r] = (j == 0) ? s : h2max(a[r], s);
                }
            }
            const float dtf = (float)(tap - 1);
            #pragma unroll
            for (int r = 0; r < 4; ++r) {
                const float mx = fmaxf(__low2float(a[r]), __high2float(a[r]));
                acc[r][mi] += fmaxf(0.0f, mx + wv[r].w * dtf);   // relu/max/+const commute
            }
        }
    }
    #pragma unroll
    for (int r = 0; r < 4; ++r) {
        float* dst = feat + ((size_t)bt * NC + c0 + 64 * r) * NM + m0;
        *(float4*)dst = make_float4(acc[r][0], acc[r][1], acc[r][2], acc[r][3]);
    }
}

extern "C" void kernel_launch(void* const* d_in, const int* in_sizes, int n_in,
                              void* d_out, int out_size, void* d_ws, size_t ws_size,
                              hipStream_t stream) {
    const float* xyzs = (const float*)d_in[0];
    const float* wd   = (const float*)d_in[1];
    float* out_xyz = (float*)d_out;
    float* featp   = out_xyz + NB * NT * NM * 3;         // new_features region
    unsigned int* dispw = (unsigned int*)d_ws;           // 12288*48*4 B = 2.36 MB
    hipLaunchKernelGGL(fps_kernel, dim3(NB * NT), dim3(256), 0, stream, xyzs, out_xyz);
    hipLaunchKernelGGL(bq_kernel, dim3(NB * NT * NM * 3 / 4), dim3(256), 0, stream,
                       xyzs, out_xyz, dispw);
    hipLaunchKernelGGL(conv_kernel, dim3(1024), dim3(256), 0, stream,
                       dispw, wd, featp);
}